// Round 1
// baseline (780.015 us; speedup 1.0000x reference)
//
#include <hip/hip_runtime.h>

#define DEV __device__ __forceinline__
typedef unsigned short u16;
typedef unsigned int u32;
typedef __bf16 bf16x8 __attribute__((ext_vector_type(8)));
typedef float f32x4 __attribute__((ext_vector_type(4)));

static constexpr int B = 8192, T = 90, F = 7, H = 128, D1 = 128, D2 = 64, NOUT = 30;

DEV float fexp2(float x) { return __builtin_amdgcn_exp2f(x); }
DEV float frcp(float x) { return __builtin_amdgcn_rcpf(x); }
DEV float frsq(float x) { return __builtin_amdgcn_rsqf(x); }
DEV float sigm(float x) { return frcp(1.f + fexp2(-1.44269504088896341f * x)); }
DEV float tanh_(float x) { return 2.f * frcp(1.f + fexp2(-2.88539008177792681f * x)) - 1.f; }
DEV u16 f2bfbits(float f) { __bf16 b = (__bf16)f; return __builtin_bit_cast(u16, b); }
DEV float bfbits2f(u32 u) { return __builtin_bit_cast(float, u << 16); }

DEV float wave_sum(float v) {
#pragma unroll
    for (int m = 32; m; m >>= 1) v += __shfl_xor(v, m, 64);
    return v;
}

// ---------------------------------------------------------------------------
// Stage 1: y = LN(x @ W_in^T + b_in) -> ln0 [B*T, 128] bf16.
// One wave per row; lane handles cols 2l, 2l+1 (packed u32 store).
// ---------------------------------------------------------------------------
__global__ __launch_bounds__(256) void s1_proj_ln(
    const float* __restrict__ x, const float* __restrict__ W_in,
    const float* __restrict__ b_in, const float* __restrict__ g_in,
    const float* __restrict__ be_in, u16* __restrict__ ln0) {
    const int wave = threadIdx.x >> 6, lane = threadIdx.x & 63;
    const long row = (long)blockIdx.x * 4 + wave;  // < B*T (737280 % 4 == 0)
    const float* xr = x + row * F;
    float xv[F];
#pragma unroll
    for (int f = 0; f < F; ++f) xv[f] = xr[f];  // row is wave-uniform -> s_loads
    const int h0 = 2 * lane;
    const float* w0 = W_in + (long)h0 * F;
    float y0 = b_in[h0], y1 = b_in[h0 + 1];
#pragma unroll
    for (int f = 0; f < F; ++f) { y0 += xv[f] * w0[f]; y1 += xv[f] * w0[F + f]; }
    const float s = wave_sum(y0 + y1);
    const float q = wave_sum(y0 * y0 + y1 * y1);
    const float mu = s * (1.f / 128.f);
    const float var = q * (1.f / 128.f) - mu * mu;
    const float rstd = frsq(var + 1e-5f);
    const float o0 = (y0 - mu) * rstd * g_in[h0] + be_in[h0];
    const float o1 = (y1 - mu) * rstd * g_in[h0 + 1] + be_in[h0 + 1];
    const u32 packed = (u32)f2bfbits(o0) | ((u32)f2bfbits(o1) << 16);
    ((u32*)ln0)[row * 64 + lane] = packed;
}

// ---------------------------------------------------------------------------
// Recurrent LSTM layer, input projection fused.
//   xin: [B, T, 128] bf16.  Wih/Whh: [512,128] fp32 row-major (gate order i,f,g,o).
//   Block: 512 thr (8 waves), 32 batch rows, grid 256 (1 block/CU).
//   Wave w owns h-cols [16w,16w+16): B-frags for both matrices live in VGPRs.
//   MFMA 16x16x32 bf16. A-layout: A[m=lane&15][k=quad*8+j]. C/D: col=lane&15,
//   row=quad*4+reg (m89/m91-verified).
// ---------------------------------------------------------------------------
template <int WRITE_HS, int WRITE_LAST>
__global__ __launch_bounds__(512, 2) void lstm_rec(
    const float* __restrict__ Wih, const float* __restrict__ Whh,
    const float* __restrict__ bih, const float* __restrict__ bhh,
    const u16* __restrict__ xin, u16* __restrict__ hs, u16* __restrict__ hlast) {
    // ln tile double buffer in chunked A-order: chunk (kk8,m) = 8 bf16 of row m,
    // k in [8*kk8, 8*kk8+8). chunk index = kk8*32 + m, 16 B each.
    __shared__ __align__(16) u16 s_x[2][32 * 128];
    __shared__ __align__(16) u16 s_h[32][136];  // natural layout, +8 pad (2-way = free)

    const int tid = threadIdx.x;
    const int wave = tid >> 6, lane = tid & 63, quad = lane >> 4, n16 = lane & 15;
    const int b0 = blockIdx.x * 32;

    for (int i = tid; i < 32 * 136; i += 512) ((u16*)s_h)[i] = 0;  // h_0 = 0

    // Load weight B-fragments: B[k][n] = W[gate*128 + 16w + n][k];
    // lane holds n = n16, k = kk*32 + quad*8 + j  (8 consecutive floats).
    bf16x8 bWih[4][4], bWhh[4][4];
    float bias[4];
#pragma unroll
    for (int g = 0; g < 4; ++g) {
        const int wrow = g * 128 + 16 * wave + n16;
        bias[g] = bih[wrow] + bhh[wrow];
#pragma unroll
        for (int kk = 0; kk < 4; ++kk) {
            const float* pi = Wih + (long)wrow * 128 + kk * 32 + quad * 8;
            const float* ph = Whh + (long)wrow * 128 + kk * 32 + quad * 8;
            bf16x8 bi, bh;
#pragma unroll
            for (int j = 0; j < 8; ++j) { bi[j] = (__bf16)pi[j]; bh[j] = (__bf16)ph[j]; }
            bWih[g][kk] = bi; bWhh[g][kk] = bh;
        }
    }

    float c[2][4];
#pragma unroll
    for (int mt = 0; mt < 2; ++mt)
#pragma unroll
        for (int r = 0; r < 4; ++r) c[mt][r] = 0.f;

    // Prologue: stage ln tile t=0. thread tid <-> chunk tid (m=tid&31, kk8=tid>>5).
    {
        const int m = tid & 31, kk8 = tid >> 5;
        const uint4 v = *(const uint4*)(xin + ((size_t)(b0 + m) * T + 0) * 128 + kk8 * 8);
        *(uint4*)&s_x[0][tid * 8] = v;
    }

#pragma unroll 1
    for (int t = 0; t < T; ++t) {
        __syncthreads();  // barrier A: s_x[t&1] staged, s_h holds h_{t-1}
        const u16* cur = s_x[t & 1];

        if (WRITE_HS && t > 0) {  // flush h_{t-1} coalesced (b128 read, dwordx4 store)
            const int m = tid >> 4, c16 = tid & 15;
            const uint4 v = *(const uint4*)&s_h[m][c16 * 8];
            *(uint4*)(hs + ((size_t)(b0 + m) * T + (t - 1)) * 128 + c16 * 8) = v;
        }
        uint4 pre = {};
        const bool hasPre = (t + 1 < T);
        if (hasPre) {  // prefetch next ln tile into registers; LDS commit at tail
            const int m = tid & 31, kk8 = tid >> 5;
            pre = *(const uint4*)(xin + ((size_t)(b0 + m) * T + (t + 1)) * 128 + kk8 * 8);
        }

        f32x4 acc[2][4];
#pragma unroll
        for (int mt = 0; mt < 2; ++mt)
#pragma unroll
            for (int g = 0; g < 4; ++g) acc[mt][g] = (f32x4){bias[g], bias[g], bias[g], bias[g]};

#pragma unroll
        for (int kk = 0; kk < 4; ++kk) {
#pragma unroll
            for (int mt = 0; mt < 2; ++mt) {
                const bf16x8 aln = *(const bf16x8*)&cur[((kk * 4 + quad) * 32 + mt * 16 + n16) * 8];
                const bf16x8 ah = *(const bf16x8*)&s_h[mt * 16 + n16][kk * 32 + quad * 8];
#pragma unroll
                for (int g = 0; g < 4; ++g) {
                    acc[mt][g] = __builtin_amdgcn_mfma_f32_16x16x32_bf16(aln, bWih[g][kk], acc[mt][g], 0, 0, 0);
                    acc[mt][g] = __builtin_amdgcn_mfma_f32_16x16x32_bf16(ah, bWhh[g][kk], acc[mt][g], 0, 0, 0);
                }
            }
        }

        u16 hbits[2][4];
#pragma unroll
        for (int mt = 0; mt < 2; ++mt)
#pragma unroll
            for (int r = 0; r < 4; ++r) {
                const float xi = acc[mt][0][r], xf = acc[mt][1][r];
                const float xg = acc[mt][2][r], xo = acc[mt][3][r];
                const float cn = sigm(xf) * c[mt][r] + sigm(xi) * tanh_(xg);
                c[mt][r] = cn;
                hbits[mt][r] = f2bfbits(sigm(xo) * tanh_(cn));
            }

        __syncthreads();  // barrier B: everyone done reading s_h / s_x[t&1]
#pragma unroll
        for (int mt = 0; mt < 2; ++mt)
#pragma unroll
            for (int r = 0; r < 4; ++r)
                s_h[mt * 16 + quad * 4 + r][16 * wave + n16] = hbits[mt][r];
        if (hasPre) *(uint4*)&s_x[(t + 1) & 1][tid * 8] = pre;
    }
    __syncthreads();
    {
        const int m = tid >> 4, c16 = tid & 15;
        const uint4 v = *(const uint4*)&s_h[m][c16 * 8];
        if (WRITE_HS)
            *(uint4*)(hs + ((size_t)(b0 + m) * T + (T - 1)) * 128 + c16 * 8) = v;
        if (WRITE_LAST)
            *(uint4*)(hlast + (size_t)(b0 + m) * 128 + c16 * 8) = v;
    }
}

// ---------------------------------------------------------------------------
// Head: out = relu(relu(LN(h_last) @ Wd1^T + b1) @ Wd2^T + b2) @ Wd3^T + b3.
// One wave per row, staged through LDS.
// ---------------------------------------------------------------------------
__global__ __launch_bounds__(256) void dense_head(
    const u16* __restrict__ hlast, const float* __restrict__ g_ln,
    const float* __restrict__ be_ln, const float* __restrict__ W_d1,
    const float* __restrict__ b_d1, const float* __restrict__ W_d2,
    const float* __restrict__ b_d2, const float* __restrict__ W_d3,
    const float* __restrict__ b_d3, float* __restrict__ out) {
    __shared__ float s_ln[4][128];
    __shared__ float s_d1[4][128];
    __shared__ float s_d2[4][64];
    const int wave = threadIdx.x >> 6, lane = threadIdx.x & 63;
    const long row = (long)blockIdx.x * 4 + wave;

    const u32 packed = ((const u32*)hlast)[row * 64 + lane];
    float v0 = bfbits2f(packed & 0xffffu), v1 = bfbits2f(packed >> 16);
    const float s = wave_sum(v0 + v1);
    const float q = wave_sum(v0 * v0 + v1 * v1);
    const float mu = s * (1.f / 128.f);
    const float rstd = frsq(q * (1.f / 128.f) - mu * mu + 1e-5f);
    const int h0 = 2 * lane;
    s_ln[wave][h0] = (v0 - mu) * rstd * g_ln[h0] + be_ln[h0];
    s_ln[wave][h0 + 1] = (v1 - mu) * rstd * g_ln[h0 + 1] + be_ln[h0 + 1];
    __syncthreads();

    const float4* lv = (const float4*)s_ln[wave];
#pragma unroll
    for (int half = 0; half < 2; ++half) {
        const int o = lane + 64 * half;
        float a = b_d1[o];
        const float4* wr = (const float4*)(W_d1 + (long)o * 128);
#pragma unroll
        for (int k = 0; k < 32; ++k) {
            const float4 wv = wr[k], xv = lv[k];
            a += wv.x * xv.x + wv.y * xv.y + wv.z * xv.z + wv.w * xv.w;
        }
        s_d1[wave][o] = fmaxf(a, 0.f);
    }
    __syncthreads();

    const float4* dv = (const float4*)s_d1[wave];
    {
        float a = b_d2[lane];
        const float4* wr = (const float4*)(W_d2 + (long)lane * 128);
#pragma unroll
        for (int k = 0; k < 32; ++k) {
            const float4 wv = wr[k], xv = dv[k];
            a += wv.x * xv.x + wv.y * xv.y + wv.z * xv.z + wv.w * xv.w;
        }
        s_d2[wave][lane] = fmaxf(a, 0.f);
    }
    __syncthreads();

    if (lane < NOUT) {
        float a = b_d3[lane];
        const float4* wr = (const float4*)(W_d3 + (long)lane * 64);
        const float4* xv2 = (const float4*)s_d2[wave];
#pragma unroll
        for (int k = 0; k < 16; ++k) {
            const float4 wv = wr[k], xv = xv2[k];
            a += wv.x * xv.x + wv.y * xv.y + wv.z * xv.z + wv.w * xv.w;
        }
        out[row * NOUT + lane] = a;
    }
}

// ---------------------------------------------------------------------------
extern "C" void kernel_launch(void* const* d_in, const int* in_sizes, int n_in,
                              void* d_out, int out_size, void* d_ws, size_t ws_size,
                              hipStream_t stream) {
    const float* x = (const float*)d_in[0];
    const float* W_in = (const float*)d_in[1];
    const float* b_in = (const float*)d_in[2];
    const float* g_in = (const float*)d_in[3];
    const float* be_in = (const float*)d_in[4];
    const float* Wih0 = (const float*)d_in[5];
    const float* Whh0 = (const float*)d_in[6];
    const float* bih0 = (const float*)d_in[7];
    const float* bhh0 = (const float*)d_in[8];
    const float* Wih1 = (const float*)d_in[9];
    const float* Whh1 = (const float*)d_in[10];
    const float* bih1 = (const float*)d_in[11];
    const float* bhh1 = (const float*)d_in[12];
    const float* g_ln = (const float*)d_in[13];
    const float* be_ln = (const float*)d_in[14];
    const float* W_d1 = (const float*)d_in[15];
    const float* b_d1 = (const float*)d_in[16];
    const float* W_d2 = (const float*)d_in[17];
    const float* b_d2 = (const float*)d_in[18];
    const float* W_d3 = (const float*)d_in[19];
    const float* b_d3 = (const float*)d_in[20];
    float* out = (float*)d_out;

    const size_t SZ = (size_t)B * T * H;  // bf16 elements per [B,T,128] buffer
    u16* ln0 = (u16*)d_ws;
    // If workspace allows, keep hs0 separate; otherwise alias onto ln0
    // (safe: within a block, hs0 writes at t-1 trail ln0 reads at t+1; blocks
    // own disjoint batch rows).
    const bool sep = ws_size >= (2 * SZ + (size_t)B * H) * sizeof(u16) + 64;
    u16* hs0 = sep ? (ln0 + SZ) : ln0;
    u16* hlast = ln0 + (sep ? 2 * SZ : SZ);

    s1_proj_ln<<<(B * T) / 4, 256, 0, stream>>>(x, W_in, b_in, g_in, be_in, ln0);
    lstm_rec<1, 0><<<B / 32, 512, 0, stream>>>(Wih0, Whh0, bih0, bhh0, ln0, hs0, nullptr);
    lstm_rec<0, 1><<<B / 32, 512, 0, stream>>>(Wih1, Whh1, bih1, bhh1, hs0, nullptr, hlast);
    dense_head<<<B / 4, 256, 0, stream>>>(hlast, g_ln, be_ln, W_d1, b_d1, W_d2, b_d2,
                                          W_d3, b_d3, out);
}

// Round 3
// 628.463 us; speedup vs baseline: 1.2411x; 1.2411x over previous
//
#include <hip/hip_runtime.h>

#define DEV __device__ __forceinline__
typedef unsigned short u16;
typedef unsigned int u32;
typedef __bf16 bf16x8 __attribute__((ext_vector_type(8)));
typedef float f32x4 __attribute__((ext_vector_type(4)));

static constexpr int B = 8192, T = 90, F = 7, H = 128, D1 = 128, D2 = 64, NOUT = 30;

DEV float fexp2(float x) { return __builtin_amdgcn_exp2f(x); }
DEV float frcp(float x) { return __builtin_amdgcn_rcpf(x); }
DEV float frsq(float x) { return __builtin_amdgcn_rsqf(x); }
DEV float sigm(float x) { return frcp(1.f + fexp2(-1.44269504088896341f * x)); }
DEV float tanh_(float x) { return 2.f * frcp(1.f + fexp2(-2.88539008177792681f * x)) - 1.f; }
DEV u16 f2bfbits(float f) { __bf16 b = (__bf16)f; return __builtin_bit_cast(u16, b); }
DEV float bfbits2f(u32 u) { return __builtin_bit_cast(float, u << 16); }

DEV float wave_sum(float v) {
#pragma unroll
    for (int m = 32; m; m >>= 1) v += __shfl_xor(v, m, 64);
    return v;
}

// ---------------------------------------------------------------------------
// Stage 1: y = LN(x @ W_in^T + b_in) -> ln0 [B*T, 128] bf16.
// Wave processes 90 rows with its two W_in columns in registers.
// ---------------------------------------------------------------------------
__global__ __launch_bounds__(256) void s1_proj_ln(
    const float* __restrict__ x, const float* __restrict__ W_in,
    const float* __restrict__ b_in, const float* __restrict__ g_in,
    const float* __restrict__ be_in, u16* __restrict__ ln0) {
    const int wave = threadIdx.x >> 6, lane = threadIdx.x & 63;
    const long row0 = (long)blockIdx.x * 360 + wave * 90;  // 2048*360 = B*T
    const int h0 = 2 * lane;
    float w0[F], w1[F];
#pragma unroll
    for (int f = 0; f < F; ++f) { w0[f] = W_in[(long)h0 * F + f]; w1[f] = W_in[(long)(h0 + 1) * F + f]; }
    const float bb0 = b_in[h0], bb1 = b_in[h0 + 1];
    const float gg0 = g_in[h0], gg1 = g_in[h0 + 1];
    const float ee0 = be_in[h0], ee1 = be_in[h0 + 1];

#pragma unroll 2
    for (int i = 0; i < 90; ++i) {
        const long row = row0 + i;
        const float* xr = x + row * F;
        float xv[F];
#pragma unroll
        for (int f = 0; f < F; ++f) xv[f] = xr[f];
        float y0 = bb0, y1 = bb1;
#pragma unroll
        for (int f = 0; f < F; ++f) { y0 += xv[f] * w0[f]; y1 += xv[f] * w1[f]; }
        const float s = wave_sum(y0 + y1);
        const float q = wave_sum(y0 * y0 + y1 * y1);
        const float mu = s * (1.f / 128.f);
        const float rstd = frsq(q * (1.f / 128.f) - mu * mu + 1e-5f);
        const float o0 = (y0 - mu) * rstd * gg0 + ee0;
        const float o1 = (y1 - mu) * rstd * gg1 + ee1;
        ((u32*)ln0)[row * 64 + lane] = (u32)f2bfbits(o0) | ((u32)f2bfbits(o1) << 16);
    }
}

// ---------------------------------------------------------------------------
// Recurrent LSTM layer, input projection fused. 512 thr (8 waves), 32 rows
// (2 m-tiles of 16), grid 256 (1 block/CU — weights-in-VGPR force this).
// s_h DOUBLE-BUFFERED by t-parity -> ONE barrier per step. Both s_x and s_h
// use chunked A-order: per 16-row tile, chunk(kk8,m) = 8 bf16 of row m,
// k-octet kk8; chunk index = kk8*16 + m.
// MFMA 16x16x32 bf16; A[m=lane&15][k=quad*8+j]; C/D col=lane&15,row=quad*4+reg.
// ---------------------------------------------------------------------------
template <int WRITE_HS, int WRITE_LAST>
__global__ __launch_bounds__(512, 2) void lstm_rec(
    const float* __restrict__ Wih, const float* __restrict__ Whh,
    const float* __restrict__ bih, const float* __restrict__ bhh,
    const u16* __restrict__ xin, u16* __restrict__ hs, u16* __restrict__ hlast) {
    __shared__ __align__(16) u16 s_x[2][2][16 * 128];  // [par][tile][chunks] 16 KB
    __shared__ __align__(16) u16 s_h[2][2][16 * 128];  // [par][tile][chunks] 16 KB

    const int tid = threadIdx.x;
    const int wave = tid >> 6, lane = tid & 63, quad = lane >> 4, n16 = lane & 15;
    const int b0 = blockIdx.x * 32;

    // h_{-1} = 0 lives at parity 1 (read when t=0). Exactly 2 tiles * 16*128 u16.
    for (int i = tid; i < 2 * 16 * 128; i += 512) ((u16*)s_h[1])[i] = 0;

    // Weight B-fragments in VGPRs: B[k][n]=W[gate*128+16w+n][k]; lane n=n16,
    // k = kk*32 + quad*8 + j.
    bf16x8 bWih[4][4], bWhh[4][4];
    float bias[4];
#pragma unroll
    for (int g = 0; g < 4; ++g) {
        const int wrow = g * 128 + 16 * wave + n16;
        bias[g] = bih[wrow] + bhh[wrow];
#pragma unroll
        for (int kk = 0; kk < 4; ++kk) {
            const float* pi = Wih + (long)wrow * 128 + kk * 32 + quad * 8;
            const float* ph = Whh + (long)wrow * 128 + kk * 32 + quad * 8;
            bf16x8 bi, bh;
#pragma unroll
            for (int j = 0; j < 8; ++j) { bi[j] = (__bf16)pi[j]; bh[j] = (__bf16)ph[j]; }
            bWih[g][kk] = bi; bWhh[g][kk] = bh;
        }
    }

    const f32x4 zero4 = {0.f, 0.f, 0.f, 0.f};
    float c[2][4];
#pragma unroll
    for (int mt = 0; mt < 2; ++mt)
#pragma unroll
        for (int r = 0; r < 4; ++r) c[mt][r] = 0.f;

    // Staging map (x prefetch): thread <-> (tile, chunk), LDS-linear stores.
    const int stile = tid >> 8, sinner = tid & 255;
    const int sm = sinner & 15, skk8 = sinner >> 4;
    const u16* gsrc = xin + (size_t)(b0 + stile * 16 + sm) * T * 128 + skk8 * 8;
    // Flush map: uint4/thread, 256 thr cover a full 16x128 tile (4 KB).
    // fm fastest -> consecutive lanes read consecutive LDS chunks (conflict-free);
    // global stores scatter over 16 rows but every row's full 256 B is written
    // each step, so L2 assembles full dirty lines (HBM sees useful bytes only).
    const int ftile = tid >> 8, finner = tid & 255;
    const int fm = finner & 15, fkk8 = finner >> 4;
    const int fldsoff = (fkk8 * 16 + fm) * 8;  // u16 index
    const size_t fgrow = (size_t)(b0 + ftile * 16 + fm) * T;
    const int fgcol = fkk8 * 8;

    {  // stage x(0) into parity 0
        const uint4 v = *(const uint4*)gsrc;
        *(uint4*)&s_x[0][stile][sinner * 8] = v;
    }
    __syncthreads();

#pragma unroll 1
    for (int t = 0; t < T; ++t) {
        const int par = t & 1;
        // prefetch x(t+1) -> regs (committed to LDS at tail, drained by barrier)
        uint4 pre = {};
        const bool hasPre = (t + 1 < T);
        if (hasPre) pre = *(const uint4*)(gsrc + (size_t)(t + 1) * 128);
        // flush h(t-1) from the buffer nobody writes this step
        if (WRITE_HS && t > 0) {
            const uint4 hv = *(const uint4*)&s_h[par ^ 1][ftile][fldsoff];
            *(uint4*)(hs + (fgrow + (t - 1)) * 128 + fgcol) = hv;
        }

        f32x4 acc[2][4];
#pragma unroll
        for (int mt = 0; mt < 2; ++mt) {
            bf16x8 aln[4], ah[4];
#pragma unroll
            for (int kk = 0; kk < 4; ++kk) {
                aln[kk] = *(const bf16x8*)&s_x[par][mt][((kk * 4 + quad) * 16 + n16) * 8];
                ah[kk] = *(const bf16x8*)&s_h[par ^ 1][mt][((kk * 4 + quad) * 16 + n16) * 8];
            }
#pragma unroll
            for (int g = 0; g < 4; ++g) {
                f32x4 a = __builtin_amdgcn_mfma_f32_16x16x32_bf16(aln[0], bWih[g][0], zero4, 0, 0, 0);
                a = __builtin_amdgcn_mfma_f32_16x16x32_bf16(ah[0], bWhh[g][0], a, 0, 0, 0);
#pragma unroll
                for (int kk = 1; kk < 4; ++kk) {
                    a = __builtin_amdgcn_mfma_f32_16x16x32_bf16(aln[kk], bWih[g][kk], a, 0, 0, 0);
                    a = __builtin_amdgcn_mfma_f32_16x16x32_bf16(ah[kk], bWhh[g][kk], a, 0, 0, 0);
                }
                acc[mt][g] = a;
            }
        }

        // gates + h-write into s_h[par] (read by others only after the barrier)
#pragma unroll
        for (int mt = 0; mt < 2; ++mt)
#pragma unroll
            for (int r = 0; r < 4; ++r) {
                const float xi = acc[mt][0][r] + bias[0];
                const float xf = acc[mt][1][r] + bias[1];
                const float xg = acc[mt][2][r] + bias[2];
                const float xo = acc[mt][3][r] + bias[3];
                const float cn = sigm(xf) * c[mt][r] + sigm(xi) * tanh_(xg);
                c[mt][r] = cn;
                const float so = sigm(xo);
                const float rr = frcp(1.f + fexp2(-2.88539008177792681f * cn));
                const float hv = __builtin_fmaf(2.f * so, rr, -so);  // so*tanh(cn)
                // element (row=quad*4+r, col=16w+n16) -> chunk ((col>>3)*16+row)
                s_h[par][mt][((2 * wave + (n16 >> 3)) * 16 + (quad * 4 + r)) * 8 + (n16 & 7)] =
                    f2bfbits(hv);
            }
        if (hasPre) *(uint4*)&s_x[par ^ 1][stile][sinner * 8] = pre;
        __syncthreads();
    }
    {  // epilogue: h(T-1) lives at parity (T-1)&1 = 1
        const uint4 hv = *(const uint4*)&s_h[1][ftile][fldsoff];
        if (WRITE_HS) *(uint4*)(hs + (fgrow + (T - 1)) * 128 + fgcol) = hv;
        if (WRITE_LAST) *(uint4*)(hlast + (size_t)(b0 + ftile * 16 + fm) * 128 + fgcol) = hv;
    }
}

// ---------------------------------------------------------------------------
// Head: 4 rows per wave (weights amortized 4x), 16 rows per block, grid 512.
// ---------------------------------------------------------------------------
__global__ __launch_bounds__(256) void dense_head(
    const u16* __restrict__ hlast, const float* __restrict__ g_ln,
    const float* __restrict__ be_ln, const float* __restrict__ W_d1,
    const float* __restrict__ b_d1, const float* __restrict__ W_d2,
    const float* __restrict__ b_d2, const float* __restrict__ W_d3,
    const float* __restrict__ b_d3, float* __restrict__ out) {
    __shared__ float s_ln[16][128];
    __shared__ float s_d1[16][128];
    __shared__ float s_d2[16][64];
    const int wave = threadIdx.x >> 6, lane = threadIdx.x & 63;
    const long base = (long)blockIdx.x * 16;
    const int R = wave * 4;

#pragma unroll
    for (int rr = 0; rr < 4; ++rr) {
        const long row = base + R + rr;
        const u32 packed = ((const u32*)hlast)[row * 64 + lane];
        float v0 = bfbits2f(packed & 0xffffu), v1 = bfbits2f(packed >> 16);
        const float s = wave_sum(v0 + v1);
        const float q = wave_sum(v0 * v0 + v1 * v1);
        const float mu = s * (1.f / 128.f);
        const float rstd = frsq(q * (1.f / 128.f) - mu * mu + 1e-5f);
        const int h0 = 2 * lane;
        s_ln[R + rr][h0] = (v0 - mu) * rstd * g_ln[h0] + be_ln[h0];
        s_ln[R + rr][h0 + 1] = (v1 - mu) * rstd * g_ln[h0 + 1] + be_ln[h0 + 1];
    }
    __syncthreads();

#pragma unroll
    for (int half = 0; half < 2; ++half) {
        const int o = lane + 64 * half;
        float a[4] = {b_d1[o], b_d1[o], b_d1[o], b_d1[o]};
        const float4* wr = (const float4*)(W_d1 + (long)o * 128);
#pragma unroll 8
        for (int k = 0; k < 32; ++k) {
            const float4 wv = wr[k];
#pragma unroll
            for (int rr = 0; rr < 4; ++rr) {
                const float4 xv = ((const float4*)s_ln[R + rr])[k];
                a[rr] += wv.x * xv.x + wv.y * xv.y + wv.z * xv.z + wv.w * xv.w;
            }
        }
#pragma unroll
        for (int rr = 0; rr < 4; ++rr) s_d1[R + rr][o] = fmaxf(a[rr], 0.f);
    }
    __syncthreads();

    {
        float a[4] = {b_d2[lane], b_d2[lane], b_d2[lane], b_d2[lane]};
        const float4* wr = (const float4*)(W_d2 + (long)lane * 128);
#pragma unroll 8
        for (int k = 0; k < 32; ++k) {
            const float4 wv = wr[k];
#pragma unroll
            for (int rr = 0; rr < 4; ++rr) {
                const float4 xv = ((const float4*)s_d1[R + rr])[k];
                a[rr] += wv.x * xv.x + wv.y * xv.y + wv.z * xv.z + wv.w * xv.w;
            }
        }
#pragma unroll
        for (int rr = 0; rr < 4; ++rr) s_d2[R + rr][lane] = fmaxf(a[rr], 0.f);
    }
    __syncthreads();

    if (lane < NOUT) {
        float a[4] = {b_d3[lane], b_d3[lane], b_d3[lane], b_d3[lane]};
        const float4* wr = (const float4*)(W_d3 + (long)lane * 64);
#pragma unroll
        for (int k = 0; k < 16; ++k) {
            const float4 wv = wr[k];
#pragma unroll
            for (int rr = 0; rr < 4; ++rr) {
                const float4 xv = ((const float4*)s_d2[R + rr])[k];
                a[rr] += wv.x * xv.x + wv.y * xv.y + wv.z * xv.z + wv.w * xv.w;
            }
        }
#pragma unroll
        for (int rr = 0; rr < 4; ++rr) out[(base + R + rr) * NOUT + lane] = a[rr];
    }
}

// ---------------------------------------------------------------------------
extern "C" void kernel_launch(void* const* d_in, const int* in_sizes, int n_in,
                              void* d_out, int out_size, void* d_ws, size_t ws_size,
                              hipStream_t stream) {
    const float* x = (const float*)d_in[0];
    const float* W_in = (const float*)d_in[1];
    const float* b_in = (const float*)d_in[2];
    const float* g_in = (const float*)d_in[3];
    const float* be_in = (const float*)d_in[4];
    const float* Wih0 = (const float*)d_in[5];
    const float* Whh0 = (const float*)d_in[6];
    const float* bih0 = (const float*)d_in[7];
    const float* bhh0 = (const float*)d_in[8];
    const float* Wih1 = (const float*)d_in[9];
    const float* Whh1 = (const float*)d_in[10];
    const float* bih1 = (const float*)d_in[11];
    const float* bhh1 = (const float*)d_in[12];
    const float* g_ln = (const float*)d_in[13];
    const float* be_ln = (const float*)d_in[14];
    const float* W_d1 = (const float*)d_in[15];
    const float* b_d1 = (const float*)d_in[16];
    const float* W_d2 = (const float*)d_in[17];
    const float* b_d2 = (const float*)d_in[18];
    const float* W_d3 = (const float*)d_in[19];
    const float* b_d3 = (const float*)d_in[20];
    float* out = (float*)d_out;

    const size_t SZ = (size_t)B * T * H;  // bf16 elements per [B,T,128] buffer
    u16* ln0 = (u16*)d_ws;
    const bool sep = ws_size >= (2 * SZ + (size_t)B * H) * sizeof(u16) + 64;
    u16* hs0 = sep ? (ln0 + SZ) : ln0;
    u16* hlast = ln0 + (sep ? 2 * SZ : SZ);

    s1_proj_ln<<<2048, 256, 0, stream>>>(x, W_in, b_in, g_in, be_in, ln0);
    lstm_rec<1, 0><<<B / 32, 512, 0, stream>>>(Wih0, Whh0, bih0, bhh0, ln0, hs0, nullptr);
    lstm_rec<0, 1><<<B / 32, 512, 0, stream>>>(Wih1, Whh1, bih1, bhh1, hs0, nullptr, hlast);
    dense_head<<<B / 16, 256, 0, stream>>>(hlast, g_ln, be_ln, W_d1, b_d1, W_d2, b_d2,
                                           W_d3, b_d3, out);
}

// Round 4
// 554.255 us; speedup vs baseline: 1.4073x; 1.1339x over previous
//
#include <hip/hip_runtime.h>

#define DEV __device__ __forceinline__
typedef unsigned short u16;
typedef unsigned int u32;
typedef __bf16 bf16x8 __attribute__((ext_vector_type(8)));
typedef float f32x4 __attribute__((ext_vector_type(4)));

static constexpr int B = 8192, T = 90, F = 7, H = 128, NOUT = 30;

DEV float fexp2(float x) { return __builtin_amdgcn_exp2f(x); }
DEV float frcp(float x) { return __builtin_amdgcn_rcpf(x); }
DEV float frsq(float x) { return __builtin_amdgcn_rsqf(x); }
DEV float sigm(float x) { return frcp(1.f + fexp2(-1.44269504088896341f * x)); }
DEV u16 f2bfbits(float f) { __bf16 b = (__bf16)f; return __builtin_bit_cast(u16, b); }
DEV float bfbits2f(u32 u) { return __builtin_bit_cast(float, u << 16); }
DEV u32 pk2(float a, float b) { return (u32)f2bfbits(a) | ((u32)f2bfbits(b) << 16); }

DEV float wave_sum(float v) {
#pragma unroll
    for (int m = 32; m; m >>= 1) v += __shfl_xor(v, m, 64);
    return v;
}

// ---------------------------------------------------------------------------
// prep_aux: one 512-thread block.
//   aux[0..6]=m (mean rows of W_in), aux[7]=mean(b_in), aux[8+7c+d]=Q=(W_in^T
//   W_in)/128, aux[64..70]=p=(W_in^T b_in)/128, aux[72]=mean(b_in^2).
//   Uhat[512][32] bf16: cols 0-6 = Wih0 diag(g) W_in, 7 = Wih0 (g.*b_in),
//   8 = Wih0 g, 9 = Wih0 be, 10..31 = 0.  Then layer-1 x-gates = Uhat . z with
//   z = [rstd*x(7), rstd, -rstd*mu, 1, 0...] — exactly Wih0 . LN(W_in x + b_in).
// ---------------------------------------------------------------------------
__global__ __launch_bounds__(512) void prep_aux(
    const float* __restrict__ W_in, const float* __restrict__ b_in,
    const float* __restrict__ g_in, const float* __restrict__ be_in,
    const float* __restrict__ Wih0, float* __restrict__ aux, u16* __restrict__ Uhat) {
    const int tid = threadIdx.x;
    if (tid < 7) {
        float sm = 0.f, sp = 0.f;
        for (int h = 0; h < 128; ++h) { const float w = W_in[h * 7 + tid]; sm += w; sp += w * b_in[h]; }
        aux[tid] = sm * (1.f / 128.f); aux[64 + tid] = sp * (1.f / 128.f);
    } else if (tid < 56) {
        const int cd = tid - 7, cc = cd / 7, dd = cd % 7;
        float s = 0.f;
        for (int h = 0; h < 128; ++h) s += W_in[h * 7 + cc] * W_in[h * 7 + dd];
        aux[8 + cd] = s * (1.f / 128.f);
    } else if (tid == 56) {
        float s = 0.f; for (int h = 0; h < 128; ++h) s += b_in[h];
        aux[7] = s * (1.f / 128.f);
    } else if (tid == 57) {
        float s = 0.f; for (int h = 0; h < 128; ++h) s += b_in[h] * b_in[h];
        aux[72] = s * (1.f / 128.f);
    }
    float acc[10];
#pragma unroll
    for (int i = 0; i < 10; ++i) acc[i] = 0.f;
    const float* wr = Wih0 + (long)tid * 128;
    for (int h = 0; h < 128; ++h) {
        const float wv = wr[h], wg = wv * g_in[h];
#pragma unroll
        for (int cc = 0; cc < 7; ++cc) acc[cc] += wg * W_in[h * 7 + cc];
        acc[7] += wg * b_in[h]; acc[8] += wg; acc[9] += wv * be_in[h];
    }
    u16* dst = Uhat + tid * 32;
#pragma unroll
    for (int cc = 0; cc < 10; ++cc) dst[cc] = f2bfbits(acc[cc]);
#pragma unroll
    for (int cc = 10; cc < 32; ++cc) dst[cc] = 0;
}

// ---------------------------------------------------------------------------
// prep_stats: per (b,t): rstd and -rstd*mu from closed-form mean/var of
// LN input (no 128-wide pass needed). stats[b*T+t] = (rstd, -rstd*mu).
// ---------------------------------------------------------------------------
__global__ __launch_bounds__(256) void prep_stats(
    const float* __restrict__ x, const float* __restrict__ aux,
    float2* __restrict__ stats) {
    __shared__ float sa[80];
    const int tid = threadIdx.x;
    if (tid < 80) sa[tid] = aux[tid];
    __syncthreads();
    const long idx = (long)blockIdx.x * 256 + tid;
    const float* xr = x + idx * 7;
    float xv[7];
#pragma unroll
    for (int cc = 0; cc < 7; ++cc) xv[cc] = xr[cc];
    float mu = sa[7];
#pragma unroll
    for (int cc = 0; cc < 7; ++cc) mu += sa[cc] * xv[cc];
    float q = sa[72];
#pragma unroll
    for (int cc = 0; cc < 7; ++cc) {
        float tacc = 2.f * sa[64 + cc];
#pragma unroll
        for (int dd = 0; dd < 7; ++dd) tacc += sa[8 + cc * 7 + dd] * xv[dd];
        q += xv[cc] * tacc;
    }
    const float rstd = frsq(q - mu * mu + 1e-5f);
    stats[idx] = make_float2(rstd, -rstd * mu);
}

// ---------------------------------------------------------------------------
// Layer-1 LSTM: x-side is the K=32 augmented-z MFMA (1 MFMA vs 4), h-side
// K=128. 512 thr / 32 rows / grid 256. One barrier per step; s_h parity-
// double-buffered; gates interleaved per m-tile for cross-wave pipe overlap.
// ---------------------------------------------------------------------------
__global__ __launch_bounds__(512, 2) void lstm_rec_l1(
    const float* __restrict__ x, const float2* __restrict__ stats,
    const u16* __restrict__ Uhat, const float* __restrict__ Whh,
    const float* __restrict__ bih, const float* __restrict__ bhh,
    u16* __restrict__ hs) {
    __shared__ __align__(16) u16 s_z[2][2][4][16][8];  // [par][mt][kk8][m][8] 4 KB
    __shared__ __align__(16) u16 s_h[2][2][16 * 128];  // [par][mt][chunks] 16 KB

    const int tid = threadIdx.x;
    const int wave = tid >> 6, lane = tid & 63, quad = lane >> 4, n16 = lane & 15;
    const int b0 = blockIdx.x * 32;

    for (int i = tid; i < 2 * 2 * 4 * 16 * 8; i += 512) ((u16*)s_z)[i] = 0;
    for (int i = tid; i < 2 * 16 * 128; i += 512) ((u16*)s_h[1])[i] = 0;

    bf16x8 bU[4], bWhh[4][4];
    float bias[4];
#pragma unroll
    for (int g = 0; g < 4; ++g) {
        const int wrow = g * 128 + 16 * wave + n16;
        bias[g] = bih[wrow] + bhh[wrow];
        bU[g] = *(const bf16x8*)&Uhat[wrow * 32 + quad * 8];
#pragma unroll
        for (int kk = 0; kk < 4; ++kk) {
            const float* ph = Whh + (long)wrow * 128 + kk * 32 + quad * 8;
            bf16x8 bh;
#pragma unroll
            for (int j = 0; j < 8; ++j) bh[j] = (__bf16)ph[j];
            bWhh[g][kk] = bh;
        }
    }

    const f32x4 zero4 = {0.f, 0.f, 0.f, 0.f};
    float c[2][4];
#pragma unroll
    for (int mt = 0; mt < 2; ++mt)
#pragma unroll
        for (int r = 0; r < 4; ++r) c[mt][r] = 0.f;

    // staging: 8 lanes/wave (balanced), 64 units total cover 32 rows x 2 chunks
    const bool stager = (lane < 8);
    const int tau = wave * 8 + lane;
    const int srow = tau & 31, skk8 = tau >> 5;
    const int smt = srow >> 4, sm = srow & 15;
    const long srowg = (long)(b0 + srow) * T;

    // flush map: 512 thr x uint4 cover both 16x128 tiles
    const int ftile = tid >> 8, finner = tid & 255;
    const int fm = finner & 15, fkk8 = finner >> 4;
    const int fldsoff = (fkk8 * 16 + fm) * 8;
    const size_t fgrow = (size_t)(b0 + ftile * 16 + fm) * T;
    const int fgcol = fkk8 * 8;

    __syncthreads();  // zero-init visible before prologue staging stores

    if (stager) {  // stage z(0) into parity 0
        const float2 st0 = stats[srowg];
        u32 p0, p1, p2, p3;
        if (skk8 == 0) {
            const float* xp = x + srowg * 7;
            const float rs = st0.x;
            p0 = pk2(rs * xp[0], rs * xp[1]); p1 = pk2(rs * xp[2], rs * xp[3]);
            p2 = pk2(rs * xp[4], rs * xp[5]); p3 = pk2(rs * xp[6], rs);
        } else { p0 = pk2(st0.y, 1.f); p1 = 0; p2 = 0; p3 = 0; }
        *(uint4*)&s_z[0][smt][skk8][sm][0] = (uint4){p0, p1, p2, p3};
    }
    __syncthreads();

#pragma unroll 1
    for (int t = 0; t < T; ++t) {
        const int par = t & 1;
        const int t1 = t + 1;
        const bool hasPre = stager && (t1 < T);
        float2 nst = {};
        float nx[7];
        if (hasPre) {
            nst = stats[srowg + t1];
            if (skk8 == 0) {
                const float* xp = x + (srowg + t1) * 7;
#pragma unroll
                for (int j = 0; j < 7; ++j) nx[j] = xp[j];
            }
        }
        if (t > 0) {  // flush h(t-1) from the idle buffer
            const uint4 hv = *(const uint4*)&s_h[par ^ 1][ftile][fldsoff];
            *(uint4*)(hs + (fgrow + (t - 1)) * 128 + fgcol) = hv;
        }

#pragma unroll
        for (int mt = 0; mt < 2; ++mt) {
            const bf16x8 az = *(const bf16x8*)&s_z[par][mt][quad][n16][0];
            bf16x8 ah[4];
#pragma unroll
            for (int kk = 0; kk < 4; ++kk)
                ah[kk] = *(const bf16x8*)&s_h[par ^ 1][mt][((kk * 4 + quad) * 16 + n16) * 8];
            f32x4 acc[4];
#pragma unroll
            for (int g = 0; g < 4; ++g) {
                f32x4 a = __builtin_amdgcn_mfma_f32_16x16x32_bf16(az, bU[g], zero4, 0, 0, 0);
#pragma unroll
                for (int kk = 0; kk < 4; ++kk)
                    a = __builtin_amdgcn_mfma_f32_16x16x32_bf16(ah[kk], bWhh[g][kk], a, 0, 0, 0);
                acc[g] = a;
            }
#pragma unroll
            for (int r = 0; r < 4; ++r) {
                const float xi = acc[0][r] + bias[0];
                const float xf = acc[1][r] + bias[1];
                const float xg = acc[2][r] + bias[2];
                const float xo = acc[3][r] + bias[3];
                const float tg = 2.f * frcp(1.f + fexp2(-2.88539008177792681f * xg)) - 1.f;
                const float cn = sigm(xf) * c[mt][r] + sigm(xi) * tg;
                c[mt][r] = cn;
                const float so = sigm(xo);
                const float rr = frcp(1.f + fexp2(-2.88539008177792681f * cn));
                const float hv = __builtin_fmaf(2.f * so, rr, -so);  // so*tanh(cn)
                s_h[par][mt][((2 * wave + (n16 >> 3)) * 16 + (quad * 4 + r)) * 8 + (n16 & 7)] =
                    f2bfbits(hv);
            }
        }

        if (hasPre) {  // commit z(t+1)
            u32 p0, p1, p2, p3;
            if (skk8 == 0) {
                const float rs = nst.x;
                p0 = pk2(rs * nx[0], rs * nx[1]); p1 = pk2(rs * nx[2], rs * nx[3]);
                p2 = pk2(rs * nx[4], rs * nx[5]); p3 = pk2(rs * nx[6], rs);
            } else { p0 = pk2(nst.y, 1.f); p1 = 0; p2 = 0; p3 = 0; }
            *(uint4*)&s_z[par ^ 1][smt][skk8][sm][0] = (uint4){p0, p1, p2, p3};
        }
        __syncthreads();
    }
    {  // epilogue: h(T-1) at parity 1
        const uint4 hv = *(const uint4*)&s_h[1][ftile][fldsoff];
        *(uint4*)(hs + (fgrow + (T - 1)) * 128 + fgcol) = hv;
    }
}

// ---------------------------------------------------------------------------
// Layer-2 LSTM: input hs0 [B,T,128] bf16 (full K=128 both sides). Same step
// structure; writes only hlast.
// ---------------------------------------------------------------------------
__global__ __launch_bounds__(512, 2) void lstm_rec_l2(
    const float* __restrict__ Wih, const float* __restrict__ Whh,
    const float* __restrict__ bih, const float* __restrict__ bhh,
    const u16* __restrict__ xin, u16* __restrict__ hlast) {
    __shared__ __align__(16) u16 s_x[2][2][16 * 128];
    __shared__ __align__(16) u16 s_h[2][2][16 * 128];

    const int tid = threadIdx.x;
    const int wave = tid >> 6, lane = tid & 63, quad = lane >> 4, n16 = lane & 15;
    const int b0 = blockIdx.x * 32;

    for (int i = tid; i < 2 * 16 * 128; i += 512) ((u16*)s_h[1])[i] = 0;

    bf16x8 bWih[4][4], bWhh[4][4];
    float bias[4];
#pragma unroll
    for (int g = 0; g < 4; ++g) {
        const int wrow = g * 128 + 16 * wave + n16;
        bias[g] = bih[wrow] + bhh[wrow];
#pragma unroll
        for (int kk = 0; kk < 4; ++kk) {
            const float* pi = Wih + (long)wrow * 128 + kk * 32 + quad * 8;
            const float* ph = Whh + (long)wrow * 128 + kk * 32 + quad * 8;
            bf16x8 bi, bh;
#pragma unroll
            for (int j = 0; j < 8; ++j) { bi[j] = (__bf16)pi[j]; bh[j] = (__bf16)ph[j]; }
            bWih[g][kk] = bi; bWhh[g][kk] = bh;
        }
    }

    const f32x4 zero4 = {0.f, 0.f, 0.f, 0.f};
    float c[2][4];
#pragma unroll
    for (int mt = 0; mt < 2; ++mt)
#pragma unroll
        for (int r = 0; r < 4; ++r) c[mt][r] = 0.f;

    const int stile = tid >> 8, sinner = tid & 255;
    const int sm = sinner & 15, skk8 = sinner >> 4;
    const u16* gsrc = xin + (size_t)(b0 + stile * 16 + sm) * T * 128 + skk8 * 8;
    const int ftile = tid >> 8, finner = tid & 255;
    const int fm = finner & 15, fkk8 = finner >> 4;
    const int fldsoff = (fkk8 * 16 + fm) * 8;
    const int fgcol = fkk8 * 8;

    {
        const uint4 v = *(const uint4*)gsrc;
        *(uint4*)&s_x[0][stile][sinner * 8] = v;
    }
    __syncthreads();

#pragma unroll 1
    for (int t = 0; t < T; ++t) {
        const int par = t & 1;
        uint4 pre = {};
        const bool hasPre = (t + 1 < T);
        if (hasPre) pre = *(const uint4*)(gsrc + (size_t)(t + 1) * 128);

#pragma unroll
        for (int mt = 0; mt < 2; ++mt) {
            bf16x8 aln[4], ah[4];
#pragma unroll
            for (int kk = 0; kk < 4; ++kk) {
                aln[kk] = *(const bf16x8*)&s_x[par][mt][((kk * 4 + quad) * 16 + n16) * 8];
                ah[kk] = *(const bf16x8*)&s_h[par ^ 1][mt][((kk * 4 + quad) * 16 + n16) * 8];
            }
            f32x4 acc[4];
#pragma unroll
            for (int g = 0; g < 4; ++g) {
                f32x4 a = __builtin_amdgcn_mfma_f32_16x16x32_bf16(aln[0], bWih[g][0], zero4, 0, 0, 0);
                a = __builtin_amdgcn_mfma_f32_16x16x32_bf16(ah[0], bWhh[g][0], a, 0, 0, 0);
#pragma unroll
                for (int kk = 1; kk < 4; ++kk) {
                    a = __builtin_amdgcn_mfma_f32_16x16x32_bf16(aln[kk], bWih[g][kk], a, 0, 0, 0);
                    a = __builtin_amdgcn_mfma_f32_16x16x32_bf16(ah[kk], bWhh[g][kk], a, 0, 0, 0);
                }
                acc[g] = a;
            }
#pragma unroll
            for (int r = 0; r < 4; ++r) {
                const float xi = acc[0][r] + bias[0];
                const float xf = acc[1][r] + bias[1];
                const float xg = acc[2][r] + bias[2];
                const float xo = acc[3][r] + bias[3];
                const float tg = 2.f * frcp(1.f + fexp2(-2.88539008177792681f * xg)) - 1.f;
                const float cn = sigm(xf) * c[mt][r] + sigm(xi) * tg;
                c[mt][r] = cn;
                const float so = sigm(xo);
                const float rr = frcp(1.f + fexp2(-2.88539008177792681f * cn));
                const float hv = __builtin_fmaf(2.f * so, rr, -so);
                s_h[par][mt][((2 * wave + (n16 >> 3)) * 16 + (quad * 4 + r)) * 8 + (n16 & 7)] =
                    f2bfbits(hv);
            }
        }
        if (hasPre) *(uint4*)&s_x[par ^ 1][stile][sinner * 8] = pre;
        __syncthreads();
    }
    {
        const uint4 hv = *(const uint4*)&s_h[1][ftile][fldsoff];
        *(uint4*)(hlast + (size_t)(b0 + ftile * 16 + fm) * 128 + fgcol) = hv;
    }
}

// ---------------------------------------------------------------------------
// Head: 4 rows per wave, 16 rows per block, grid 512.
// ---------------------------------------------------------------------------
__global__ __launch_bounds__(256) void dense_head(
    const u16* __restrict__ hlast, const float* __restrict__ g_ln,
    const float* __restrict__ be_ln, const float* __restrict__ W_d1,
    const float* __restrict__ b_d1, const float* __restrict__ W_d2,
    const float* __restrict__ b_d2, const float* __restrict__ W_d3,
    const float* __restrict__ b_d3, float* __restrict__ out) {
    __shared__ float s_ln[16][128];
    __shared__ float s_d1[16][128];
    __shared__ float s_d2[16][64];
    const int wave = threadIdx.x >> 6, lane = threadIdx.x & 63;
    const long base = (long)blockIdx.x * 16;
    const int R = wave * 4;

#pragma unroll
    for (int rr = 0; rr < 4; ++rr) {
        const long row = base + R + rr;
        const u32 packed = ((const u32*)hlast)[row * 64 + lane];
        float v0 = bfbits2f(packed & 0xffffu), v1 = bfbits2f(packed >> 16);
        const float s = wave_sum(v0 + v1);
        const float q = wave_sum(v0 * v0 + v1 * v1);
        const float mu = s * (1.f / 128.f);
        const float rstd = frsq(q * (1.f / 128.f) - mu * mu + 1e-5f);
        const int h0 = 2 * lane;
        s_ln[R + rr][h0] = (v0 - mu) * rstd * g_ln[h0] + be_ln[h0];
        s_ln[R + rr][h0 + 1] = (v1 - mu) * rstd * g_ln[h0 + 1] + be_ln[h0 + 1];
    }
    __syncthreads();

#pragma unroll
    for (int half = 0; half < 2; ++half) {
        const int o = lane + 64 * half;
        float a[4] = {b_d1[o], b_d1[o], b_d1[o], b_d1[o]};
        const float4* wr = (const float4*)(W_d1 + (long)o * 128);
#pragma unroll 8
        for (int k = 0; k < 32; ++k) {
            const float4 wv = wr[k];
#pragma unroll
            for (int rr = 0; rr < 4; ++rr) {
                const float4 xv = ((const float4*)s_ln[R + rr])[k];
                a[rr] += wv.x * xv.x + wv.y * xv.y + wv.z * xv.z + wv.w * xv.w;
            }
        }
#pragma unroll
        for (int rr = 0; rr < 4; ++rr) s_d1[R + rr][o] = fmaxf(a[rr], 0.f);
    }
    __syncthreads();

    {
        float a[4] = {b_d2[lane], b_d2[lane], b_d2[lane], b_d2[lane]};
        const float4* wr = (const float4*)(W_d2 + (long)lane * 128);
#pragma unroll 8
        for (int k = 0; k < 32; ++k) {
            const float4 wv = wr[k];
#pragma unroll
            for (int rr = 0; rr < 4; ++rr) {
                const float4 xv = ((const float4*)s_d1[R + rr])[k];
                a[rr] += wv.x * xv.x + wv.y * xv.y + wv.z * xv.z + wv.w * xv.w;
            }
        }
#pragma unroll
        for (int rr = 0; rr < 4; ++rr) s_d2[R + rr][lane] = fmaxf(a[rr], 0.f);
    }
    __syncthreads();

    if (lane < NOUT) {
        float a[4] = {b_d3[lane], b_d3[lane], b_d3[lane], b_d3[lane]};
        const float4* wr = (const float4*)(W_d3 + (long)lane * 64);
#pragma unroll
        for (int k = 0; k < 16; ++k) {
            const float4 wv = wr[k];
#pragma unroll
            for (int rr = 0; rr < 4; ++rr) {
                const float4 xv = ((const float4*)s_d2[R + rr])[k];
                a[rr] += wv.x * xv.x + wv.y * xv.y + wv.z * xv.z + wv.w * xv.w;
            }
        }
#pragma unroll
        for (int rr = 0; rr < 4; ++rr) out[(base + R + rr) * NOUT + lane] = a[rr];
    }
}

// ---------------------------------------------------------------------------
extern "C" void kernel_launch(void* const* d_in, const int* in_sizes, int n_in,
                              void* d_out, int out_size, void* d_ws, size_t ws_size,
                              hipStream_t stream) {
    const float* x = (const float*)d_in[0];
    const float* W_in = (const float*)d_in[1];
    const float* b_in = (const float*)d_in[2];
    const float* g_in = (const float*)d_in[3];
    const float* be_in = (const float*)d_in[4];
    const float* Wih0 = (const float*)d_in[5];
    const float* Whh0 = (const float*)d_in[6];
    const float* bih0 = (const float*)d_in[7];
    const float* bhh0 = (const float*)d_in[8];
    const float* Wih1 = (const float*)d_in[9];
    const float* Whh1 = (const float*)d_in[10];
    const float* bih1 = (const float*)d_in[11];
    const float* bhh1 = (const float*)d_in[12];
    const float* g_ln = (const float*)d_in[13];
    const float* be_ln = (const float*)d_in[14];
    const float* W_d1 = (const float*)d_in[15];
    const float* b_d1 = (const float*)d_in[16];
    const float* W_d2 = (const float*)d_in[17];
    const float* b_d2 = (const float*)d_in[18];
    const float* W_d3 = (const float*)d_in[19];
    const float* b_d3 = (const float*)d_in[20];
    float* out = (float*)d_out;

    // workspace layout (~197 MB): aux | Uhat | stats | hs0 | hlast
    char* w = (char*)d_ws;
    float* aux = (float*)w;               w += 512;
    u16* Uhat = (u16*)w;                  w += 512 * 32 * sizeof(u16);
    float2* stats = (float2*)w;           w += (size_t)B * T * sizeof(float2);
    u16* hs0 = (u16*)w;                   w += (size_t)B * T * H * sizeof(u16);
    u16* hlast = (u16*)w;

    prep_aux<<<1, 512, 0, stream>>>(W_in, b_in, g_in, be_in, Wih0, aux, Uhat);
    prep_stats<<<(B * T) / 256, 256, 0, stream>>>(x, aux, stats);
    lstm_rec_l1<<<B / 32, 512, 0, stream>>>(x, stats, Uhat, Whh0, bih0, bhh0, hs0);
    lstm_rec_l2<<<B / 32, 512, 0, stream>>>(Wih1, Whh1, bih1, bhh1, hs0, hlast);
    dense_head<<<B / 16, 256, 0, stream>>>(hlast, g_ln, be_ln, W_d1, b_d1, W_d2, b_d2,
                                           W_d3, b_d3, out);
}